// Round 6
// baseline (12619.865 us; speedup 1.0000x reference)
//
#include <hip/hip_runtime.h>
#include <hip/hip_fp16.h>

// ---------------------------------------------------------------------------
// 2-layer bidirectional tanh RNN, B=32, T=512, E=256, H=512.
//   prep:  fp32->fp16 conversions (+ xs transpose, bias sums)
//   gemm:  pre[d][t*32+b][j] = X @ W_ih[d]^T + bias   (fp16 MFMA)
//   rnn:   512 sequential steps; 8 blocks/dir (256 thr), each owns a 64-wide
//          j-slice of W_hh in VGPRs.  All blocks of a direction are placed on
//          ONE XCD via HW_REG_XCC_ID claiming (CAS), so the h exchange runs
//          through that XCD's shared L2 (~200 cyc) with AGENT-scope relaxed
//          atomics.  Words are SELF-TAGGED (tag<<32 | 2xfp16): no fences, no
//          flags, no cache-maintenance ops.  (R4: agent scope across XCDs =
//          stale-L2 stalls; R5: system scope = LLC ~900 cyc on the serial
//          chain. Colocation gets coherence AND L2 latency.)
// ---------------------------------------------------------------------------

#define T_ 512
#define B_ 32
#define E_ 256
#define H_ 512

using half8 = _Float16 __attribute__((ext_vector_type(8)));
using f32x4 = float __attribute__((ext_vector_type(4)));
typedef unsigned long long u64;
typedef unsigned int u32;

// workspace layout (bytes)
static constexpr size_t OFF_PRE   = 0;                         // f16 [2][16384][512]  32 MB
static constexpr size_t OFF_XH1   = 32ull << 20;               // f16 [16384][1024]    32 MB
static constexpr size_t OFF_X0H   = 64ull << 20;               // f16 [16384][256]      8 MB
static constexpr size_t OFF_W0H   = 72ull << 20;               // f16 [2][512][256]   0.5 MB
static constexpr size_t OFF_W1H   = OFF_W0H + (512ull << 10);  // f16 [2][512][1024]    2 MB
static constexpr size_t OFF_WHH   = OFF_W1H + (2ull << 20);    // f16 [2][2][512][512]  2 MB
static constexpr size_t OFF_BS    = OFF_WHH + (2ull << 20);    // f32 [2][2][512]       8 KB
static constexpr size_t OFF_HX    = OFF_BS + (8ull << 10);     // u64 [2 layer][2 dir][2 phase][32][256] 512 KB
static constexpr size_t OFF_CLAIM = OFF_HX + (512ull << 10);   // int [2 layer][16]
static constexpr size_t ZERO_SIZE = (512ull << 10) + 4096;     // hx + claim

__device__ __forceinline__ float fast_tanh(float x) {
    float cx = fminf(fmaxf(x, -9.0f), 9.0f);
    float e2 = __expf(2.0f * cx);
    return (e2 - 1.0f) * __builtin_amdgcn_rcpf(e2 + 1.0f);
}

// ---------------------------------------------------------------------------
__global__ void prep_kernel(const float* __restrict__ xs,
                            const float* __restrict__ wih0,
                            const float* __restrict__ whh0,
                            const float* __restrict__ b0,
                            const float* __restrict__ wih1,
                            const float* __restrict__ whh1,
                            const float* __restrict__ b1,
                            _Float16* __restrict__ x0h,
                            _Float16* __restrict__ w0h,
                            _Float16* __restrict__ w1h,
                            _Float16* __restrict__ whh,
                            float* __restrict__ bsum)
{
    const int N0 = T_ * B_ * E_;
    const int N1 = 2 * H_ * E_;
    const int N2 = 2 * H_ * 2*H_;
    const int N3 = 2 * H_ * H_;
    const int total = N0 + N1 + N2 + 2 * N3 + 2048;
    for (int idx = blockIdx.x * blockDim.x + threadIdx.x; idx < total;
         idx += gridDim.x * blockDim.x) {
        int i = idx;
        if (i < N0) {
            int t = i >> 13;
            int r = i & 8191;
            int b = r >> 8;
            int e = r & 255;
            x0h[i] = (_Float16)xs[((size_t)(b << 9) + t) * 256 + e];
        } else if ((i -= N0) < N1) {
            w0h[i] = (_Float16)wih0[i];
        } else if ((i -= N1) < N2) {
            w1h[i] = (_Float16)wih1[i];
        } else if ((i -= N2) < N3) {
            whh[i] = (_Float16)whh0[i];
        } else if ((i -= N3) < N3) {
            whh[N3 + i] = (_Float16)whh1[i];
        } else {
            i -= N3;               // 0..2047: [layer][dir][512]
            int layer = i >> 10;
            int r = i & 1023;
            int d = r >> 9;
            int j = r & 511;
            const float* bb = layer ? b1 : b0;
            bsum[i] = bb[d * 1024 + j] + bb[d * 1024 + 512 + j];
        }
    }
}

// ---------------------------------------------------------------------------
__global__ __launch_bounds__(256, 2)
void gemm_kernel(const _Float16* __restrict__ X,
                 const _Float16* __restrict__ W,
                 const float* __restrict__ bias,
                 _Float16* __restrict__ out, int K)
{
    __shared__ _Float16 Ash[64][72];
    __shared__ _Float16 Bsh[64][72];
    const int m0 = blockIdx.x * 64, n0 = blockIdx.y * 64, d = blockIdx.z;
    const _Float16* Wd = W + (size_t)d * 512 * K;
    const int tid = threadIdx.x;
    const int l = tid & 63, w = tid >> 6;
    const int wm = w & 1, wn = w >> 1;
    const int lm = l & 15, q = l >> 4;
    f32x4 c[2][2] = {};
    for (int kk = 0; kk < K; kk += 64) {
        for (int ci = tid; ci < 512; ci += 256) {
            int row = ci >> 3, col = (ci & 7) * 8;
            *(half8*)&Ash[row][col] =
                *(const half8*)&X[(size_t)(m0 + row) * K + kk + col];
            *(half8*)&Bsh[row][col] =
                *(const half8*)&Wd[(size_t)(n0 + row) * K + kk + col];
        }
        __syncthreads();
        for (int kt = 0; kt < 2; ++kt) {
            const int kof = kt * 32 + q * 8;
            half8 a0 = *(const half8*)&Ash[wm * 32 + lm][kof];
            half8 a1 = *(const half8*)&Ash[wm * 32 + 16 + lm][kof];
            half8 b0f = *(const half8*)&Bsh[wn * 32 + lm][kof];
            half8 b1f = *(const half8*)&Bsh[wn * 32 + 16 + lm][kof];
            c[0][0] = __builtin_amdgcn_mfma_f32_16x16x32_f16(a0, b0f, c[0][0], 0, 0, 0);
            c[0][1] = __builtin_amdgcn_mfma_f32_16x16x32_f16(a0, b1f, c[0][1], 0, 0, 0);
            c[1][0] = __builtin_amdgcn_mfma_f32_16x16x32_f16(a1, b0f, c[1][0], 0, 0, 0);
            c[1][1] = __builtin_amdgcn_mfma_f32_16x16x32_f16(a1, b1f, c[1][1], 0, 0, 0);
        }
        __syncthreads();
    }
    _Float16* outd = out + (size_t)d * 16384 * 512;
    for (int mi = 0; mi < 2; ++mi)
        for (int ni = 0; ni < 2; ++ni) {
            int col = n0 + wn * 32 + ni * 16 + lm;
            float bv = bias[d * 512 + col];
            for (int r = 0; r < 4; ++r) {
                int rowm = m0 + wm * 32 + mi * 16 + q * 4 + r;
                outd[(size_t)rowm * 512 + col] = (_Float16)(c[mi][ni][r] + bv);
            }
        }
}

// ---------------------------------------------------------------------------
// hx per dir: [2 phase][32 b][256 jp] u64; word = (tag<<32)|(f16 j=2jp+1)<<16|(f16 j=2jp)
// Roles: 8 blocks/dir; role r: d = r>>3, g = r&7 (j-slice [g*64, g*64+64)).
// XCD claiming: thread 0 reads HW_REG_XCC_ID, CASes its XCD onto a direction;
// first 8 blocks of that XCD take roles, everyone else returns immediately.
__global__ __launch_bounds__(256)
void rnn_kernel(const _Float16* __restrict__ pre,   // [2][16384][512] f16
                const _Float16* __restrict__ whh,   // this layer: [2][512][512] f16
                u64* __restrict__ hx,               // [2 dir][2 phase][32][256] u64
                int* __restrict__ claim,            // [16] this layer (zeroed)
                _Float16* __restrict__ xh1,         // layer0 out: [16384][1024] f16
                float* __restrict__ dout,           // final output buffer
                int layer)
{
    __shared__ uint4 As[64 * 33];                   // A-frag staging, 33.8 KB
    __shared__ int role_sh;
    if (threadIdx.x == 0) {
        unsigned xcc;
        asm volatile("s_getreg_b32 %0, hwreg(HW_REG_XCC_ID)" : "=s"(xcc));
        const int me = (int)(xcc & 0xF) + 1;
        int role = -1;
        int w0 = atomicCAS(&claim[0], 0, me);
        if ((w0 == 0 ? me : w0) == me) {
            int slot = atomicAdd(&claim[2], 1);
            if (slot < 8) role = slot;              // dir 0
        }
        if (role < 0) {
            int w1 = atomicCAS(&claim[1], 0, me);
            if ((w1 == 0 ? me : w1) == me) {
                int slot = atomicAdd(&claim[3], 1);
                if (slot < 8) role = 8 + slot;      // dir 1
            }
        }
        role_sh = role;
    }
    __syncthreads();
    const int role = role_sh;
    if (role < 0) return;

    const int d = role >> 3, g = role & 7;
    const int tid = threadIdx.x, wv = tid >> 6, l = tid & 63;
    const int lm = l & 15, q = l >> 4;
    const int wm = wv & 1, wn = wv >> 1;
    const int jb = g * 64 + wn * 32;                // wave's 32-col slice base
    const int bA = wm * 16 + lm;                    // A-frag row (b)
    const int bq = wm * 16 + q * 4;                 // C/D row base (b)

    // Preload W B-fragments (2 x 16-col sets): lane holds W[j][k=kt*32+q*8+e]
    half8 Bf[2][16];
#pragma unroll
    for (int nt = 0; nt < 2; ++nt) {
        const _Float16* wrow = whh + ((size_t)d * 512 + jb + nt * 16 + lm) * 512;
#pragma unroll
        for (int kt = 0; kt < 16; ++kt)
            Bf[nt][kt] = *(const half8*)&wrow[kt * 32 + q * 8];
    }

    u64* hbd = hx + (size_t)d * 2 * 8192;
    const int jp0 = (jb + (lm & ~1)) >> 1;          // publish col (nt=0); nt=1: +8
    const int scat_base = ((tid >> 2) * 33) * 4 + (tid & 3);
    u32* AsW = (u32*)As;

    for (int s = 0; s < T_; ++s) {
        const int t = d ? (T_ - 1 - s) : s;

        // ---- pre prefetch (latency hides under the poll) ----
        const _Float16* prow = pre + ((size_t)d * 16384 + (size_t)t * B_) * 512 + jb + lm;
        _Float16 pv[2][4];
#pragma unroll
        for (int nt = 0; nt < 2; ++nt)
#pragma unroll
            for (int r = 0; r < 4; ++r)
                pv[nt][r] = prow[(size_t)(bq + r) * 512 + nt * 16];

        // ---- coalesced tagged gather (agent scope -> XCD-local L2) ----
        const u64* src = hbd + (size_t)(s & 1) * 8192 + tid;
        const unsigned tag = (unsigned)s;
        u64 wvv[32];
#pragma unroll
        for (int i = 0; i < 32; ++i)
            wvv[i] = __hip_atomic_load(&src[i * 256],
                                       __ATOMIC_RELAXED, __HIP_MEMORY_SCOPE_AGENT);
        unsigned miss = 0;
#pragma unroll
        for (int i = 0; i < 32; ++i)
            if (__any((unsigned)(wvv[i] >> 32) != tag)) miss |= (1u << i);
        while (miss) {                               // selective column retry
            int i = __ffs(miss) - 1;
            wvv[i] = __hip_atomic_load(&src[i * 256],
                                       __ATOMIC_RELAXED, __HIP_MEMORY_SCOPE_AGENT);
            if (!__any((unsigned)(wvv[i] >> 32) != tag)) miss &= ~(1u << i);
        }

        // ---- LDS scatter to A-frag layout ----
        __syncthreads();   // prior step's frag reads done before overwrite
#pragma unroll
        for (int i = 0; i < 32; ++i)
            AsW[scat_base + i * 4] = (u32)wvv[i];
        __syncthreads();

        // ---- MFMA: 2 n-tiles x 2 interleaved chains ----
        f32x4 c[2][2];
#pragma unroll
        for (int nt = 0; nt < 2; ++nt)
#pragma unroll
            for (int r = 0; r < 4; ++r) {
                c[nt][0][r] = (float)pv[nt][r];
                c[nt][1][r] = 0.0f;
            }
#pragma unroll
        for (int kt = 0; kt < 16; ++kt) {
            union { uint4 u; half8 h; } cv;
            cv.u = As[(kt * 4 + q) * 33 + bA];
            c[0][kt & 1] = __builtin_amdgcn_mfma_f32_16x16x32_f16(cv.h, Bf[0][kt], c[0][kt & 1], 0, 0, 0);
            c[1][kt & 1] = __builtin_amdgcn_mfma_f32_16x16x32_f16(cv.h, Bf[1][kt], c[1][kt & 1], 0, 0, 0);
        }

        // ---- tanh + publish (critical path first) + outputs ----
        u64* dst = hbd + (size_t)((s + 1) & 1) * 8192;
        const u64 tagw = ((u64)(unsigned)(s + 1)) << 32;
        float hv[2][4];
        unsigned hb[2][4];
#pragma unroll
        for (int nt = 0; nt < 2; ++nt)
#pragma unroll
            for (int r = 0; r < 4; ++r) {
                hv[nt][r] = fast_tanh(c[nt][0][r] + c[nt][1][r]);
                union { _Float16 f; unsigned short u; } cb;
                cb.f = (_Float16)hv[nt][r];
                hb[nt][r] = cb.u;
            }
#pragma unroll
        for (int nt = 0; nt < 2; ++nt)
#pragma unroll
            for (int r = 0; r < 4; ++r) {
                unsigned p = __shfl_xor(hb[nt][r], 1, 64);
                unsigned lo = (l & 1) ? p : hb[nt][r];
                unsigned hi = (l & 1) ? hb[nt][r] : p;
                if ((r >> 1) == (l & 1)) {
                    u64 word = tagw | ((u64)hi << 16) | lo;
                    __hip_atomic_store(&dst[(size_t)(bq + r) * 256 + jp0 + nt * 8], word,
                                       __ATOMIC_RELAXED, __HIP_MEMORY_SCOPE_AGENT);
                }
            }
#pragma unroll
        for (int nt = 0; nt < 2; ++nt)
#pragma unroll
            for (int r = 0; r < 4; ++r) {
                const int j = jb + nt * 16 + lm;
                const int b = bq + r;
                if (layer == 0) {
                    xh1[((size_t)t * B_ + b) * 1024 + d * 512 + j] = (_Float16)hv[nt][r];
                } else {
                    dout[((size_t)b * T_ + t) * 1024 + d * 512 + j] = hv[nt][r];
                }
                if (s == T_ - 1) {
                    dout[16777216ull + ((size_t)(layer * 2 + d) * B_ + b) * 512 + j] = hv[nt][r];
                }
            }
    }
}

// ---------------------------------------------------------------------------
extern "C" void kernel_launch(void* const* d_in, const int* in_sizes, int n_in,
                              void* d_out, int out_size, void* d_ws, size_t ws_size,
                              hipStream_t stream)
{
    const float* xs   = (const float*)d_in[0];
    const float* wih0 = (const float*)d_in[1];
    const float* whh0 = (const float*)d_in[2];
    const float* b0   = (const float*)d_in[3];
    const float* wih1 = (const float*)d_in[4];
    const float* whh1 = (const float*)d_in[5];
    const float* b1   = (const float*)d_in[6];

    char* ws = (char*)d_ws;
    _Float16* pre  = (_Float16*)(ws + OFF_PRE);
    _Float16* xh1  = (_Float16*)(ws + OFF_XH1);
    _Float16* x0h  = (_Float16*)(ws + OFF_X0H);
    _Float16* w0h  = (_Float16*)(ws + OFF_W0H);
    _Float16* w1h  = (_Float16*)(ws + OFF_W1H);
    _Float16* whh  = (_Float16*)(ws + OFF_WHH);
    float*    bsum = (float*)(ws + OFF_BS);
    u64*      hx   = (u64*)(ws + OFF_HX);
    int*      claim= (int*)(ws + OFF_CLAIM);
    float*    out  = (float*)d_out;

    // zero tagged h buffers (h(0)=0 with tag 0) + claim state
    (void)hipMemsetAsync(ws + OFF_HX, 0, ZERO_SIZE, stream);

    prep_kernel<<<2048, 256, 0, stream>>>(xs, wih0, whh0, b0, wih1, whh1, b1,
                                          x0h, w0h, w1h, whh, bsum);

    // layer 0
    gemm_kernel<<<dim3(256, 8, 2), 256, 0, stream>>>(x0h, w0h, bsum, pre, 256);
    rnn_kernel<<<1024, 256, 0, stream>>>(pre, whh, hx, claim, xh1, out, 0);

    // layer 1
    gemm_kernel<<<dim3(256, 8, 2), 256, 0, stream>>>(xh1, w1h, bsum + 1024, pre, 1024);
    rnn_kernel<<<1024, 256, 0, stream>>>(pre, whh + 2 * 512 * 512,
                                         hx + 2 * 2 * 8192, claim + 16, xh1, out, 1);
}

// Round 7
// 11104.478 us; speedup vs baseline: 1.1365x; 1.1365x over previous
//
#include <hip/hip_runtime.h>
#include <hip/hip_fp16.h>

// ---------------------------------------------------------------------------
// 2-layer bidirectional tanh RNN, B=32, T=512, E=256, H=512.
//   prep:  fp32->fp16 conversions (+ xs transpose, bias sums)
//   gemm:  pre[d][t*32+b][j] = X @ W_ih[d]^T + bias   (fp16 MFMA)
//   rnn:   512 sequential steps; TWO blocks per direction (512 thr, 8 waves),
//          each owns a 256-col half of W_hh in VGPRs (128 regs/wave).
//          Own half of h lives in LDS; only the peer's 32 KB half is
//          exchanged via SELF-TAGGED u64 words (tag<<32 | 2xfp16), relaxed
//          SYSTEM-scope atomics (R5-proven LLC path), BATCHED re-poll
//          (R6 lesson: serial per-row retry = 31 dependent round trips).
//          Own-half MFMAs run inside the detect window to hide LLC latency.
// ---------------------------------------------------------------------------

#define T_ 512
#define B_ 32
#define E_ 256
#define H_ 512

using half8 = _Float16 __attribute__((ext_vector_type(8)));
using f32x4 = float __attribute__((ext_vector_type(4)));
typedef unsigned long long u64;
typedef unsigned int u32;

// workspace layout (bytes)
static constexpr size_t OFF_PRE   = 0;                         // f16 [2][16384][512]  32 MB
static constexpr size_t OFF_XH1   = 32ull << 20;               // f16 [16384][1024]    32 MB
static constexpr size_t OFF_X0H   = 64ull << 20;               // f16 [16384][256]      8 MB
static constexpr size_t OFF_W0H   = 72ull << 20;               // f16 [2][512][256]   0.5 MB
static constexpr size_t OFF_W1H   = OFF_W0H + (512ull << 10);  // f16 [2][512][1024]    2 MB
static constexpr size_t OFF_WHH   = OFF_W1H + (2ull << 20);    // f16 [2][2][512][512]  2 MB
static constexpr size_t OFF_BS    = OFF_WHH + (2ull << 20);    // f32 [2][2][512]       8 KB
static constexpr size_t OFF_HX    = OFF_BS + (8ull << 10);     // u64 [2 layer][2 dir][2 phase][2 half][32][128]  512 KB
static constexpr size_t ZERO_SIZE = 512ull << 10;

__device__ __forceinline__ float fast_tanh(float x) {
    float cx = fminf(fmaxf(x, -9.0f), 9.0f);
    float e2 = __expf(2.0f * cx);
    return (e2 - 1.0f) * __builtin_amdgcn_rcpf(e2 + 1.0f);
}

// ---------------------------------------------------------------------------
__global__ void prep_kernel(const float* __restrict__ xs,
                            const float* __restrict__ wih0,
                            const float* __restrict__ whh0,
                            const float* __restrict__ b0,
                            const float* __restrict__ wih1,
                            const float* __restrict__ whh1,
                            const float* __restrict__ b1,
                            _Float16* __restrict__ x0h,
                            _Float16* __restrict__ w0h,
                            _Float16* __restrict__ w1h,
                            _Float16* __restrict__ whh,
                            float* __restrict__ bsum)
{
    const int N0 = T_ * B_ * E_;
    const int N1 = 2 * H_ * E_;
    const int N2 = 2 * H_ * 2*H_;
    const int N3 = 2 * H_ * H_;
    const int total = N0 + N1 + N2 + 2 * N3 + 2048;
    for (int idx = blockIdx.x * blockDim.x + threadIdx.x; idx < total;
         idx += gridDim.x * blockDim.x) {
        int i = idx;
        if (i < N0) {
            int t = i >> 13;
            int r = i & 8191;
            int b = r >> 8;
            int e = r & 255;
            x0h[i] = (_Float16)xs[((size_t)(b << 9) + t) * 256 + e];
        } else if ((i -= N0) < N1) {
            w0h[i] = (_Float16)wih0[i];
        } else if ((i -= N1) < N2) {
            w1h[i] = (_Float16)wih1[i];
        } else if ((i -= N2) < N3) {
            whh[i] = (_Float16)whh0[i];
        } else if ((i -= N3) < N3) {
            whh[N3 + i] = (_Float16)whh1[i];
        } else {
            i -= N3;               // 0..2047: [layer][dir][512]
            int layer = i >> 10;
            int r = i & 1023;
            int d = r >> 9;
            int j = r & 511;
            const float* bb = layer ? b1 : b0;
            bsum[i] = bb[d * 1024 + j] + bb[d * 1024 + 512 + j];
        }
    }
}

// ---------------------------------------------------------------------------
__global__ __launch_bounds__(256, 2)
void gemm_kernel(const _Float16* __restrict__ X,
                 const _Float16* __restrict__ W,
                 const float* __restrict__ bias,
                 _Float16* __restrict__ out, int K)
{
    __shared__ _Float16 Ash[64][72];
    __shared__ _Float16 Bsh[64][72];
    const int m0 = blockIdx.x * 64, n0 = blockIdx.y * 64, d = blockIdx.z;
    const _Float16* Wd = W + (size_t)d * 512 * K;
    const int tid = threadIdx.x;
    const int l = tid & 63, w = tid >> 6;
    const int wm = w & 1, wn = w >> 1;
    const int lm = l & 15, q = l >> 4;
    f32x4 c[2][2] = {};
    for (int kk = 0; kk < K; kk += 64) {
        for (int ci = tid; ci < 512; ci += 256) {
            int row = ci >> 3, col = (ci & 7) * 8;
            *(half8*)&Ash[row][col] =
                *(const half8*)&X[(size_t)(m0 + row) * K + kk + col];
            *(half8*)&Bsh[row][col] =
                *(const half8*)&Wd[(size_t)(n0 + row) * K + kk + col];
        }
        __syncthreads();
        for (int kt = 0; kt < 2; ++kt) {
            const int kof = kt * 32 + q * 8;
            half8 a0 = *(const half8*)&Ash[wm * 32 + lm][kof];
            half8 a1 = *(const half8*)&Ash[wm * 32 + 16 + lm][kof];
            half8 b0f = *(const half8*)&Bsh[wn * 32 + lm][kof];
            half8 b1f = *(const half8*)&Bsh[wn * 32 + 16 + lm][kof];
            c[0][0] = __builtin_amdgcn_mfma_f32_16x16x32_f16(a0, b0f, c[0][0], 0, 0, 0);
            c[0][1] = __builtin_amdgcn_mfma_f32_16x16x32_f16(a0, b1f, c[0][1], 0, 0, 0);
            c[1][0] = __builtin_amdgcn_mfma_f32_16x16x32_f16(a1, b0f, c[1][0], 0, 0, 0);
            c[1][1] = __builtin_amdgcn_mfma_f32_16x16x32_f16(a1, b1f, c[1][1], 0, 0, 0);
        }
        __syncthreads();
    }
    _Float16* outd = out + (size_t)d * 16384 * 512;
    for (int mi = 0; mi < 2; ++mi)
        for (int ni = 0; ni < 2; ++ni) {
            int col = n0 + wn * 32 + ni * 16 + lm;
            float bv = bias[d * 512 + col];
            for (int r = 0; r < 4; ++r) {
                int rowm = m0 + wm * 32 + mi * 16 + q * 4 + r;
                outd[(size_t)rowm * 512 + col] = (_Float16)(c[mi][ni][r] + bv);
            }
        }
}

// ---------------------------------------------------------------------------
// hx per dir: [2 phase][2 half][32 b][128 jp] u64,
//   word = (tag<<32) | (f16 j=2jp+1)<<16 | (f16 j=2jp).   h(s): phase s&1, tag s.
// Block bi: d = bi>>1, half = bi&1; wave w owns cols jw = half*256 + w*32 .. +32.
// LDS As: [kg=64][b=32] uint4 (pad 33) = A-frag layout of full h(s).
//   own rows (kg in [half*32, +32)) written locally; peer rows scattered from
//   polled words.  Barrier B1 (post-scatter) doubles as the guard for the
//   own-row overwrite; B2 at step end guards next step's own-row reads.
__global__ __launch_bounds__(512, 2)
void rnn_kernel(const _Float16* __restrict__ pre,   // [2][16384][512] f16
                const _Float16* __restrict__ whh,   // this layer: [2][512][512] f16
                u64* __restrict__ hx,               // this layer: [2 dir][16384] u64
                _Float16* __restrict__ xh1,         // layer0 out: [16384][1024] f16
                float* __restrict__ dout,           // final output buffer
                int layer)
{
    __shared__ uint4 As[64 * 33];                   // 33.8 KB
    const int bi = blockIdx.x;                      // 0..3
    const int d = bi >> 1, half = bi & 1, peer = half ^ 1;
    const int tid = threadIdx.x, w = tid >> 6, l = tid & 63;
    const int lm = l & 15, q = l >> 4;
    const int jw = half * 256 + w * 32;             // wave's col base (global j)

    // B-fragments: Bf[nt][kt] = W[j = jw + nt*16 + lm][k = kt*32 + q*8 + e]
    half8 Bf[2][16];
#pragma unroll
    for (int nt = 0; nt < 2; ++nt) {
        const _Float16* wrow = whh + ((size_t)d * 512 + jw + nt * 16 + lm) * 512;
#pragma unroll
        for (int kt = 0; kt < 16; ++kt)
            Bf[nt][kt] = *(const half8*)&wrow[kt * 32 + q * 8];
    }

    u64* hdir = hx + (size_t)d * 16384;
    u32* AsW = (u32*)As;
    const int om0 = half * 8;                       // own k-tile range
    const int pm0 = peer * 8;

    // init own rows of As to h(0)=0
    for (int i = tid; i < 1024; i += 512)
        As[(half * 32 + (i >> 5)) * 33 + (i & 31)] = uint4{0, 0, 0, 0};
    __syncthreads();

    for (int s = 0; s < T_; ++s) {
        const int t = d ? (T_ - 1 - s) : s;
        const int p = s & 1;

        // ---- issue peer-half poll loads first (detect window opens) ----
        const u64* src = hdir + (size_t)p * 8192 + (size_t)peer * 4096 + tid;
        u64 w8[8];
#pragma unroll
        for (int i = 0; i < 8; ++i)
            w8[i] = __hip_atomic_load(&src[i * 512],
                                      __ATOMIC_RELAXED, __HIP_MEMORY_SCOPE_SYSTEM);

        // ---- pre prefetch (resolves by tanh time) ----
        const _Float16* prow = pre + ((size_t)d * 16384 + (size_t)t * B_) * 512 + jw;
        _Float16 pv[2][2][4];
#pragma unroll
        for (int m = 0; m < 2; ++m)
#pragma unroll
            for (int nt = 0; nt < 2; ++nt)
#pragma unroll
                for (int r = 0; r < 4; ++r)
                    pv[m][nt][r] = prow[(size_t)(m * 16 + q * 4 + r) * 512 + nt * 16 + lm];

        // ---- own-half MFMAs (hide under detect window) ----
        f32x4 acc[2][2] = {};
#pragma unroll
        for (int kk = 0; kk < 8; ++kk) {
            const int kt = om0 + kk;
            union { uint4 u; half8 h; } a0, a1;
            a0.u = As[(kt * 4 + q) * 33 + lm];
            a1.u = As[(kt * 4 + q) * 33 + 16 + lm];
            acc[0][0] = __builtin_amdgcn_mfma_f32_16x16x32_f16(a0.h, Bf[0][kt], acc[0][0], 0, 0, 0);
            acc[0][1] = __builtin_amdgcn_mfma_f32_16x16x32_f16(a0.h, Bf[1][kt], acc[0][1], 0, 0, 0);
            acc[1][0] = __builtin_amdgcn_mfma_f32_16x16x32_f16(a1.h, Bf[0][kt], acc[1][0], 0, 0, 0);
            acc[1][1] = __builtin_amdgcn_mfma_f32_16x16x32_f16(a1.h, Bf[1][kt], acc[1][1], 0, 0, 0);
        }

        // ---- batched tag poll (R6 lesson: never serialize retries) ----
        const unsigned tag = (unsigned)s;
        for (;;) {
            bool ok = true;
#pragma unroll
            for (int i = 0; i < 8; ++i)
                ok &= ((unsigned)(w8[i] >> 32) == tag);
            if (!__any(!ok)) break;
#pragma unroll
            for (int i = 0; i < 8; ++i)
                w8[i] = __hip_atomic_load(&src[i * 512],
                                          __ATOMIC_RELAXED, __HIP_MEMORY_SCOPE_SYSTEM);
        }

        // ---- scatter peer half into As peer rows ----
#pragma unroll
        for (int i = 0; i < 8; ++i) {
            const int wi = i * 512 + tid;
            const int b = wi >> 7, jpl = wi & 127;
            const int jpg = peer * 128 + jpl;
            AsW[((jpg >> 2) * 33 + b) * 4 + (jpg & 3)] = (u32)w8[i];
        }
        __syncthreads();                            // B1

        // ---- peer-half MFMAs ----
#pragma unroll
        for (int kk = 0; kk < 8; ++kk) {
            const int kt = pm0 + kk;
            union { uint4 u; half8 h; } a0, a1;
            a0.u = As[(kt * 4 + q) * 33 + lm];
            a1.u = As[(kt * 4 + q) * 33 + 16 + lm];
            acc[0][0] = __builtin_amdgcn_mfma_f32_16x16x32_f16(a0.h, Bf[0][kt], acc[0][0], 0, 0, 0);
            acc[0][1] = __builtin_amdgcn_mfma_f32_16x16x32_f16(a0.h, Bf[1][kt], acc[0][1], 0, 0, 0);
            acc[1][0] = __builtin_amdgcn_mfma_f32_16x16x32_f16(a1.h, Bf[0][kt], acc[1][0], 0, 0, 0);
            acc[1][1] = __builtin_amdgcn_mfma_f32_16x16x32_f16(a1.h, Bf[1][kt], acc[1][1], 0, 0, 0);
        }

        // ---- tanh + publish own h(s+1) (critical path) + LDS own rows ----
        u64* dst = hdir + (size_t)(p ^ 1) * 8192 + (size_t)half * 4096;
        const u64 tagw = ((u64)(unsigned)(s + 1)) << 32;
        float hvf[2][2][4];
#pragma unroll
        for (int m = 0; m < 2; ++m)
#pragma unroll
            for (int nt = 0; nt < 2; ++nt) {
                unsigned hb[4];
#pragma unroll
                for (int r = 0; r < 4; ++r) {
                    const float hv = fast_tanh(acc[m][nt][r] + (float)pv[m][nt][r]);
                    hvf[m][nt][r] = hv;
                    union { _Float16 f; unsigned short u; } cb;
                    cb.f = (_Float16)hv;
                    hb[r] = cb.u;
                }
#pragma unroll
                for (int r = 0; r < 4; ++r) {
                    const unsigned ps = __shfl_xor(hb[r], 1, 64);
                    const unsigned lo = (l & 1) ? ps : hb[r];
                    const unsigned hi = (l & 1) ? hb[r] : ps;
                    if ((r >> 1) == (l & 1)) {
                        const int b = m * 16 + q * 4 + r;
                        const int jpl = (w * 32 + nt * 16 + (lm & ~1)) >> 1;
                        const u64 word = tagw | ((u64)hi << 16) | lo;
                        __hip_atomic_store(&dst[b * 128 + jpl], word,
                                           __ATOMIC_RELAXED, __HIP_MEMORY_SCOPE_SYSTEM);
                        const int jpg = half * 128 + jpl;
                        AsW[((jpg >> 2) * 33 + b) * 4 + (jpg & 3)] = (u32)word;
                    }
                }
            }

        // ---- staged outputs ----
#pragma unroll
        for (int m = 0; m < 2; ++m)
#pragma unroll
            for (int nt = 0; nt < 2; ++nt)
#pragma unroll
                for (int r = 0; r < 4; ++r) {
                    const int b = m * 16 + q * 4 + r;
                    const int j = jw + nt * 16 + lm;
                    const float hv = hvf[m][nt][r];
                    if (layer == 0) {
                        xh1[((size_t)t * B_ + b) * 1024 + d * 512 + j] = (_Float16)hv;
                    } else {
                        dout[((size_t)b * T_ + t) * 1024 + d * 512 + j] = hv;
                    }
                    if (s == T_ - 1) {
                        dout[16777216ull + ((size_t)(layer * 2 + d) * B_ + b) * 512 + j] = hv;
                    }
                }

        __syncthreads();                            // B2
    }
}

// ---------------------------------------------------------------------------
extern "C" void kernel_launch(void* const* d_in, const int* in_sizes, int n_in,
                              void* d_out, int out_size, void* d_ws, size_t ws_size,
                              hipStream_t stream)
{
    const float* xs   = (const float*)d_in[0];
    const float* wih0 = (const float*)d_in[1];
    const float* whh0 = (const float*)d_in[2];
    const float* b0   = (const float*)d_in[3];
    const float* wih1 = (const float*)d_in[4];
    const float* whh1 = (const float*)d_in[5];
    const float* b1   = (const float*)d_in[6];

    char* ws = (char*)d_ws;
    _Float16* pre  = (_Float16*)(ws + OFF_PRE);
    _Float16* xh1  = (_Float16*)(ws + OFF_XH1);
    _Float16* x0h  = (_Float16*)(ws + OFF_X0H);
    _Float16* w0h  = (_Float16*)(ws + OFF_W0H);
    _Float16* w1h  = (_Float16*)(ws + OFF_W1H);
    _Float16* whh  = (_Float16*)(ws + OFF_WHH);
    float*    bsum = (float*)(ws + OFF_BS);
    u64*      hx   = (u64*)(ws + OFF_HX);
    float*    out  = (float*)d_out;

    // zero tagged h buffers (h(0)=0 with tag 0); ws is poisoned 0xAA
    (void)hipMemsetAsync(ws + OFF_HX, 0, ZERO_SIZE, stream);

    prep_kernel<<<2048, 256, 0, stream>>>(xs, wih0, whh0, b0, wih1, whh1, b1,
                                          x0h, w0h, w1h, whh, bsum);

    // layer 0
    gemm_kernel<<<dim3(256, 8, 2), 256, 0, stream>>>(x0h, w0h, bsum, pre, 256);
    rnn_kernel<<<4, 512, 0, stream>>>(pre, whh, hx, xh1, out, 0);

    // layer 1
    gemm_kernel<<<dim3(256, 8, 2), 256, 0, stream>>>(xh1, w1h, bsum + 1024, pre, 1024);
    rnn_kernel<<<4, 512, 0, stream>>>(pre, whh + 2 * 512 * 512,
                                      hx + 2 * 16384, xh1, out, 1);
}